// Round 1
// baseline (1510.378 us; speedup 1.0000x reference)
//
#include <hip/hip_runtime.h>
#include <math.h>

namespace {

constexpr int kB  = 4;
constexpr int kT  = 2048;
constexpr int kD  = 512;
constexpr int kE  = 4;
constexpr int kC  = 1024;
constexpr int kHE = 512;
constexpr int kO  = 512;
constexpr int kEC = kE * kC;  // 4096

constexpr int BM = 128, BN = 128, BK = 8, TM = 8, TN = 8;
// 256 threads per block: 16x16 thread grid, each thread an 8x8 microtile.

__device__ __forceinline__ float gelu_exact(float v) {
    return 0.5f * v * (1.0f + erff(v * 0.70710678118654752f));
}

// Generic batched GEMM: C[z] = op(A[z]) * B[z % zMod] (+ bias[z % zMod]) (+ gelu)
// A_IS_KM == true : A stored K-major (K x M, row stride M)  -> computes A^T * B
// A_IS_KM == false: A stored M-major (M x K, row stride K)  -> computes A * B
// MODE: 0 = plain store, 1 = +bias then exact GELU, 2 = +bias
// All of M % 128, N % 128, K % 8 are 0 for every stage here (no bounds checks).
template <bool A_IS_KM, int MODE>
__global__ __launch_bounds__(256)
void gemm_batched(const float* __restrict__ Aall, const float* __restrict__ Ball,
                  const float* __restrict__ biasAll, float* __restrict__ Call,
                  int M, int N, int K,
                  long long strideA, long long strideB, long long strideBias,
                  long long strideC, int zMod)
{
    const int z = blockIdx.z;
    const float* __restrict__ A    = Aall + (long long)z * strideA;
    const float* __restrict__ Bp   = Ball + (long long)(z % zMod) * strideB;
    const float* __restrict__ bias =
        (MODE != 0) ? (biasAll + (long long)(z % zMod) * strideBias) : nullptr;
    float* __restrict__ Cp = Call + (long long)z * strideC;

    __shared__ float As[BK][BM];
    __shared__ float Bs[BK][BN];

    const int t  = threadIdx.x;
    const int tx = t & 15;
    const int ty = t >> 4;
    const int row0 = blockIdx.y * BM;
    const int col0 = blockIdx.x * BN;

    float acc[TM][TN];
#pragma unroll
    for (int i = 0; i < TM; ++i)
#pragma unroll
        for (int j = 0; j < TN; ++j) acc[i][j] = 0.0f;

    // Staging-load index plans (all float4, fully coalesced):
    const int lakm_k = t >> 5, lakm_m = (t & 31) * 4;  // A_IS_KM: 8 rows x 128 cols
    const int lamk_m = t >> 1, lamk_k = (t & 1) * 4;   // A MxK: 128 rows x 8 cols
    const int lb_k   = t >> 5, lb_n   = (t & 31) * 4;  // B: 8 rows x 128 cols

    for (int k0 = 0; k0 < K; k0 += BK) {
        if (A_IS_KM) {
            const float4 v =
                *(const float4*)&A[(size_t)(k0 + lakm_k) * M + row0 + lakm_m];
            *(float4*)&As[lakm_k][lakm_m] = v;
        } else {
            const float4 v =
                *(const float4*)&A[(size_t)(row0 + lamk_m) * K + k0 + lamk_k];
            // transposed scatter into k-major LDS; bank pattern is 2-way (free)
            As[lamk_k + 0][lamk_m] = v.x;
            As[lamk_k + 1][lamk_m] = v.y;
            As[lamk_k + 2][lamk_m] = v.z;
            As[lamk_k + 3][lamk_m] = v.w;
        }
        {
            const float4 v =
                *(const float4*)&Bp[(size_t)(k0 + lb_k) * N + col0 + lb_n];
            *(float4*)&Bs[lb_k][lb_n] = v;
        }
        __syncthreads();

#pragma unroll
        for (int k = 0; k < BK; ++k) {
            float a[TM], b[TN];
            *(float4*)&a[0] = *(const float4*)&As[k][ty * TM];
            *(float4*)&a[4] = *(const float4*)&As[k][ty * TM + 4];
            *(float4*)&b[0] = *(const float4*)&Bs[k][tx * TN];
            *(float4*)&b[4] = *(const float4*)&Bs[k][tx * TN + 4];
#pragma unroll
            for (int i = 0; i < TM; ++i)
#pragma unroll
                for (int j = 0; j < TN; ++j)
                    acc[i][j] = fmaf(a[i], b[j], acc[i][j]);
        }
        __syncthreads();
    }

    // Epilogue: optional bias (indexed by column) + optional exact GELU.
#pragma unroll
    for (int i = 0; i < TM; ++i) {
        const size_t m = (size_t)(row0 + ty * TM + i);
        float* crow = &Cp[m * (size_t)N + col0 + tx * TN];
#pragma unroll
        for (int jj = 0; jj < TN; jj += 4) {
            float4 v = make_float4(acc[i][jj + 0], acc[i][jj + 1],
                                   acc[i][jj + 2], acc[i][jj + 3]);
            if (MODE != 0) {
                const int nb = col0 + tx * TN + jj;
                v.x += bias[nb + 0];
                v.y += bias[nb + 1];
                v.z += bias[nb + 2];
                v.w += bias[nb + 3];
            }
            if (MODE == 1) {
                v.x = gelu_exact(v.x);
                v.y = gelu_exact(v.y);
                v.z = gelu_exact(v.z);
                v.w = gelu_exact(v.w);
            }
            *(float4*)&crow[jj] = v;
        }
    }
}

}  // namespace

extern "C" void kernel_launch(void* const* d_in, const int* in_sizes, int n_in,
                              void* d_out, int out_size, void* d_ws, size_t ws_size,
                              hipStream_t stream)
{
    const float* x    = (const float*)d_in[0];  // (B,T,D)
    const float* mask = (const float*)d_in[1];  // (B,T,E,C)
    const float* comb = (const float*)d_in[2];  // (B,T,E,C)
    const float* w1   = (const float*)d_in[3];  // (E,D,HE)
    const float* b1   = (const float*)d_in[4];  // (E,HE)
    const float* w2   = (const float*)d_in[5];  // (E,HE,O)
    const float* b2   = (const float*)d_in[6];  // (O,)
    float* out = (float*)d_out;                 // (B,T,O)

    // Workspace: xd[B,EC,D] (32 MB) | h[B,EC,HE] (32 MB); y reuses xd's region.
    float* xd = (float*)d_ws;
    float* h  = xd + (size_t)kB * kEC * kD;
    float* y  = xd;

    dim3 blk(256);

    // Stage 1 (dispatch): per b, xd[ec,d] = sum_t mask[t,ec] * x[t,d]
    //   A = mask[b] stored (T x EC) K-major; B = x[b] (T x D).
    gemm_batched<true, 0><<<dim3(kD / BN, kEC / BM, kB), blk, 0, stream>>>(
        mask, x, nullptr, xd, kEC, kD, kT,
        (long long)kT * kEC, (long long)kT * kD, 0, (long long)kEC * kD, 16);

    // Stage 2 (fc1 + bias + gelu): per g=b*E+e, h = gelu(xd[g] * w1[e] + b1[e])
    gemm_batched<false, 1><<<dim3(kHE / BN, kC / BM, kB * kE), blk, 0, stream>>>(
        xd, w1, b1, h, kC, kHE, kD,
        (long long)kC * kD, (long long)kD * kHE, kHE, (long long)kC * kHE, kE);

    // Stage 3 (fc2): per g, y[g] = h[g] * w2[e]   (y overwrites xd region)
    gemm_batched<false, 0><<<dim3(kO / BN, kC / BM, kB * kE), blk, 0, stream>>>(
        h, w2, nullptr, y, kC, kO, kHE,
        (long long)kC * kHE, (long long)kHE * kO, 0, (long long)kC * kO, kE);

    // Stage 4 (combine): per b, out[t,o] = sum_ec comb[t,ec] * y[ec,o] + b2[o]
    gemm_batched<false, 2><<<dim3(kO / BN, kT / BM, kB), blk, 0, stream>>>(
        comb, y, b2, out, kT, kO, kEC,
        (long long)kT * kEC, (long long)kEC * kO, 0, (long long)kT * kO, 16);
}

// Round 2
// 500.885 us; speedup vs baseline: 3.0154x; 3.0154x over previous
//
#include <hip/hip_runtime.h>
#include <math.h>

namespace {

typedef short short8 __attribute__((ext_vector_type(8)));
typedef float f32x4 __attribute__((ext_vector_type(4)));

constexpr int kB = 4, kT = 2048, kD = 512, kE = 4, kC = 1024, kHE = 512,
              kO = 512, kEC = 4096;

__device__ __forceinline__ unsigned short f2bf(float f) {
    unsigned int u = __float_as_uint(f);
    u += 0x7fffu + ((u >> 16) & 1u);   // RNE
    return (unsigned short)(u >> 16);
}

__device__ __forceinline__ float gelu_exact(float v) {
    return 0.5f * v * (1.0f + erff(v * 0.70710678118654752f));
}

#define GLDS16(g, l)                                                      \
    __builtin_amdgcn_global_load_lds(                                     \
        (const __attribute__((address_space(1))) unsigned int*)(g),       \
        (__attribute__((address_space(3))) unsigned int*)(l), 16, 0, 0)

// ---------------------------------------------------------------------------
// Batched transpose+cast: in[z] is R x Cc fp32 -> out[z] is Cc x R bf16.
__global__ __launch_bounds__(256)
void transpose_cast(const float* __restrict__ in, unsigned short* __restrict__ out,
                    int R, int Cc, long long sIn, long long sOut)
{
    __shared__ float tile[32][33];
    const int z = blockIdx.z;
    const float* ip = in + (long long)z * sIn;
    unsigned short* op = out + (long long)z * sOut;
    const int c0 = blockIdx.x * 32, r0 = blockIdx.y * 32;
    const int tx = threadIdx.x & 31, ty = threadIdx.x >> 5;  // ty 0..7
#pragma unroll
    for (int i = 0; i < 4; ++i) {
        const int r = ty + i * 8;
        tile[r][tx] = ip[(size_t)(r0 + r) * Cc + c0 + tx];
    }
    __syncthreads();
#pragma unroll
    for (int i = 0; i < 4; ++i) {
        const int c = ty + i * 8;
        op[(size_t)(c0 + c) * R + r0 + tx] = f2bf(tile[tx][c]);
    }
}

// Plain elementwise fp32 -> bf16 (n multiple of 4).
__global__ __launch_bounds__(256)
void cast_bf16(const float* __restrict__ in, unsigned short* __restrict__ out,
               long long n)
{
    const long long i = ((long long)blockIdx.x * blockDim.x + threadIdx.x) * 4;
    if (i < n) {
        const float4 v = *(const float4*)&in[i];
        unsigned short o[4] = {f2bf(v.x), f2bf(v.y), f2bf(v.z), f2bf(v.w)};
        *(uint2*)&out[i] = *(const uint2*)o;
    }
}

// ---------------------------------------------------------------------------
// MFMA GEMM (m97 structure): C[z] = A[z%zModA] (MxK, k-contig) *
//                                   B[z%zModB]^T (NxK, k-contig)
// B element (n,k) lives at ((k>>bShift)*N + n)<<bShift | (k & mask) — with
// bShift = log2(K) this degenerates to plain n*K+k; bShift=10 handles the
// [e][O][C] segmented layout of yT in stage 4 (BK=64 never crosses a segment).
// MODE: 0 = bf16 store, 1 = bf16 store of gelu(acc+bias[n]), 3 = f32 acc+bias[n].
// M%128 == N%128 == K%64 == 0 for every stage (no bounds checks).
template <int MODE>
__global__ __launch_bounds__(256)
void mfma_gemm(const unsigned short* __restrict__ Aall,
               const unsigned short* __restrict__ Ball,
               const float* __restrict__ biasAll,
               void* __restrict__ Call,
               int M, int N, int K,
               long long sA, long long sB, long long sC,
               int zModA, int zModB, int zModBias, int biasStride, int bShift)
{
    __shared__ unsigned short As[128 * 64];
    __shared__ unsigned short Bs[128 * 64];

    const int z = blockIdx.z;
    const unsigned short* Ab = Aall + (long long)(z % zModA) * sA;
    const unsigned short* Bb = Ball + (long long)(z % zModB) * sB;
    const float* bias =
        (MODE != 0) ? biasAll + (long long)(z % zModBias) * biasStride : nullptr;

    const int t = threadIdx.x;
    const int lane = t & 63;
    const int w = t >> 6;           // wave 0..3
    const int wrow = w * 32;        // staging row block per wave
    const int l8r = lane >> 3;      // 0..7  (row within 8-row staging group)
    const int l8c = (lane & 7) * 8; // k element offset (8 bf16 = 16 B)
    const int row0 = blockIdx.y * 128;
    const int col0 = blockIdx.x * 128;

    const int wm = (w >> 1) * 64;   // wave's 64x64 quadrant
    const int wn = (w & 1) * 64;
    const int fr = lane & 15;       // fragment row/col within 16
    const int fq = (lane >> 4) * 8; // fragment k offset

    const unsigned int bMask = (1u << bShift) - 1u;

    f32x4 acc[4][4] = {};

    for (int k0 = 0; k0 < K; k0 += 64) {
#pragma unroll
        for (int r = 0; r < 4; ++r) {
            const int ar = row0 + wrow + r * 8 + l8r;
            GLDS16(Ab + (size_t)ar * K + (k0 + l8c), &As[(wrow + r * 8) * 64]);
            const int bn = col0 + wrow + r * 8 + l8r;
            const int gk = k0 + l8c;
            const size_t boff =
                (((size_t)(gk >> bShift) * N + bn) << bShift) + (gk & bMask);
            GLDS16(Bb + boff, &Bs[(wrow + r * 8) * 64]);
        }
        __syncthreads();
#pragma unroll
        for (int kk = 0; kk < 2; ++kk) {
            short8 af[4], bf[4];
#pragma unroll
            for (int i = 0; i < 4; ++i)
                af[i] = *(const short8*)&As[(wm + i * 16 + fr) * 64 + kk * 32 + fq];
#pragma unroll
            for (int j = 0; j < 4; ++j)
                bf[j] = *(const short8*)&Bs[(wn + j * 16 + fr) * 64 + kk * 32 + fq];
#pragma unroll
            for (int i = 0; i < 4; ++i)
#pragma unroll
                for (int j = 0; j < 4; ++j)
                    acc[i][j] = __builtin_amdgcn_mfma_f32_16x16x32_bf16(
                        af[i], bf[j], acc[i][j], 0, 0, 0);
        }
        __syncthreads();
    }

    // Epilogue. C/D layout: col = lane&15, row = (lane>>4)*4 + reg  [m89/m91].
    const long long cz = (long long)z * sC;
#pragma unroll
    for (int i = 0; i < 4; ++i) {
        const int rowb = row0 + wm + i * 16 + (lane >> 4) * 4;
#pragma unroll
        for (int j = 0; j < 4; ++j) {
            const int col = col0 + wn + j * 16 + fr;
            const float bv = (MODE != 0) ? bias[col] : 0.0f;
#pragma unroll
            for (int r = 0; r < 4; ++r) {
                const float v = acc[i][j][r];
                const size_t idx = (size_t)cz + (size_t)(rowb + r) * N + col;
                if (MODE == 0)
                    ((unsigned short*)Call)[idx] = f2bf(v);
                else if (MODE == 1)
                    ((unsigned short*)Call)[idx] = f2bf(gelu_exact(v + bv));
                else
                    ((float*)Call)[idx] = v + bv;
            }
        }
    }
}

}  // namespace

extern "C" void kernel_launch(void* const* d_in, const int* in_sizes, int n_in,
                              void* d_out, int out_size, void* d_ws, size_t ws_size,
                              hipStream_t stream)
{
    const float* x    = (const float*)d_in[0];  // (B,T,D)
    const float* mask = (const float*)d_in[1];  // (B,T,EC)
    const float* comb = (const float*)d_in[2];  // (B,T,EC)
    const float* w1   = (const float*)d_in[3];  // (E,D,HE)
    const float* b1   = (const float*)d_in[4];  // (E,HE)
    const float* w2   = (const float*)d_in[5];  // (E,HE,O)
    const float* b2   = (const float*)d_in[6];  // (O,)
    float* out = (float*)d_out;                 // (B,T,O) fp32

    // Workspace (bf16 elements): 108 MB total.
    unsigned short* ws    = (unsigned short*)d_ws;
    unsigned short* regA  = ws;                  // 33,554,432: maskT, then combB
    unsigned short* xT    = regA + 33554432;     //  4,194,304: [B][D][T]
    unsigned short* w1T   = xT + 4194304;        //  1,048,576: [E][HE][D]
    unsigned short* w2T   = w1T + 1048576;       //  1,048,576: [E][O][HE]
    unsigned short* xd    = w2T + 1048576;       //  8,388,608: [B][EC][D]; reused as yT [B][E][O][C]
    unsigned short* h     = xd + 8388608;        //  8,388,608: [B*E][C][HE]
    unsigned short* maskT = regA;                // [B][EC][T]
    unsigned short* combB = regA;                // [B][T][EC]
    unsigned short* yT    = xd;

    dim3 blk(256);

    // --- conversions ---
    transpose_cast<<<dim3(kEC / 32, kT / 32, kB), blk, 0, stream>>>(
        mask, maskT, kT, kEC, (long long)kT * kEC, (long long)kT * kEC);
    transpose_cast<<<dim3(kD / 32, kT / 32, kB), blk, 0, stream>>>(
        x, xT, kT, kD, (long long)kT * kD, (long long)kT * kD);
    transpose_cast<<<dim3(kHE / 32, kD / 32, kE), blk, 0, stream>>>(
        w1, w1T, kD, kHE, (long long)kD * kHE, (long long)kD * kHE);
    transpose_cast<<<dim3(kO / 32, kHE / 32, kE), blk, 0, stream>>>(
        w2, w2T, kHE, kO, (long long)kHE * kO, (long long)kHE * kO);

    // --- stage 1: xd[b][ec][d] = sum_t maskT[b][ec][t] * xT[b][d][t] ---
    mfma_gemm<0><<<dim3(kD / 128, kEC / 128, kB), blk, 0, stream>>>(
        maskT, xT, nullptr, xd, kEC, kD, kT,
        (long long)kEC * kT, (long long)kD * kT, (long long)kEC * kD,
        kB, kB, 1, 0, 11);

    // comb cast (after stage 1 — reuses maskT's region, stream-ordered)
    cast_bf16<<<dim3(33554432 / 4 / 256), blk, 0, stream>>>(
        comb, combB, 33554432LL);

    // --- stage 2: h[g][c][he] = gelu(xd[g]*w1T[e]^T + b1[e]) ---
    mfma_gemm<1><<<dim3(kHE / 128, kC / 128, kB * kE), blk, 0, stream>>>(
        xd, w1T, b1, h, kC, kHE, kD,
        (long long)kC * kD, (long long)kHE * kD, (long long)kC * kHE,
        kB * kE, kE, kE, kHE, 9);

    // --- stage 3 (swapped): yT[g][o][c] = w2T[e]*h[g]^T ---
    mfma_gemm<0><<<dim3(kC / 128, kO / 128, kB * kE), blk, 0, stream>>>(
        w2T, h, nullptr, yT, kO, kC, kHE,
        (long long)kO * kHE, (long long)kC * kHE, (long long)kO * kC,
        kE, kB * kE, 1, 0, 9);

    // --- stage 4: out[b][t][o] = sum_ec combB[b][t][ec]*yT[b][e][o][c] + b2 ---
    mfma_gemm<3><<<dim3(kO / 128, kT / 128, kB), blk, 0, stream>>>(
        combB, yT, b2, out, kT, kO, kEC,
        (long long)kT * kEC, (long long)kE * kO * kC, (long long)kT * kO,
        kB, kB, 1, 0, 10);
}